// Round 1
// baseline (1645.981 us; speedup 1.0000x reference)
//
#include <hip/hip_runtime.h>
#include <cstdint>
#include <cstddef>

typedef unsigned short u16;
typedef unsigned char u8;

// Problem constants
constexpr int L_ = 256, B_ = 32, D_ = 2400;
constexpr int K0 = 620, K0P = 640;          // layer-0 K, padded (mult of 64)
constexpr int N0 = 9600, N0P = 9728;        // layer-0 N = 4*D, padded to 38*256
constexpr int NL = 7200, NLP = 7424;        // layers 1-3 N = 3*D, padded to 29*256
constexpr int KL = 2400, KLP = 2432;        // layers 1-3 K = D, padded to mult of 64
constexpr int MR = L_ * B_;                 // 8192 rows (32*256)

// ---- workspace carve-up (bytes; lifetimes audited against launch order) ----
constexpr size_t SZ_XBUF = (size_t)MR * KLP * 2;     // 39,845,888  bf16 x (stride 2432)
constexpr size_t SZ_UB   = (size_t)MR * N0P * 2;     // 159,383,552 bf16 U (stride 9728)
constexpr size_t OFF_XA  = 0;
constexpr size_t OFF_XB  = SZ_XBUF;
constexpr size_t OFF_U   = 2 * SZ_XBUF;
constexpr size_t WS_REQ  = OFF_U + SZ_UB;            // 239,075,328 (< 248.2 MB known-good)
// W0^T bf16 (9728,640) aliases xa tail: dead after gemm0; xa written first by scan0
constexpr size_t SZ_WT0  = (size_t)N0P * K0P * 2;    // 12,451,840
constexpr size_t OFF_WT0 = OFF_XA + SZ_XBUF - SZ_WT0;
static_assert(OFF_WT0 % 256 == 0, "");
// x0 bf16 (8192,640) aliases xb head: dead after gemm0; xb pads zeroed after gemm0
constexpr size_t SZ_X0   = (size_t)MR * K0P * 2;     // 10,485,760
static_assert(SZ_X0 <= SZ_XBUF, "");
// layers 1-3 W^T bf16 (7424,2432) alias U tail: layer-0 U dead after scan0,
// and big GEMMs write U only through stride NLP (first 121.6 MB)
constexpr size_t WT_L_OFF = (size_t)MR * NLP * 2;    // 121,634,816
static_assert(WT_L_OFF + (size_t)NLP * KLP * 2 <= SZ_UB, "WtL must fit in U tail");

typedef __bf16 bf16x8 __attribute__((ext_vector_type(8)));
typedef float floatx4 __attribute__((ext_vector_type(4)));

__device__ __forceinline__ u16 f2bf(float x) {
  unsigned u = __float_as_uint(x);
  unsigned r = 0x7fffu + ((u >> 16) & 1u);   // round-to-nearest-even
  return (u16)((u + r) >> 16);
}
__device__ __forceinline__ float bf2f(u16 v) {
  return __uint_as_float((unsigned)v << 16);
}
__device__ __forceinline__ float frcp(float x) { return __builtin_amdgcn_rcpf(x); }
__device__ __forceinline__ float fsigmoid(float x) { return frcp(1.f + __expf(-x)); }
__device__ __forceinline__ float ftanh(float x) {
  return 1.f - 2.f * frcp(__expf(2.f * x) + 1.f);   // saturates via inf/0
}

__device__ __forceinline__ void gload_lds16(const void* g, void* l) {
  __builtin_amdgcn_global_load_lds(
      (__attribute__((address_space(1))) void*)g,
      (__attribute__((address_space(3))) void*)l,
      16, 0, 0);
}

// ---- ws_size probe: if workspace too small, report its MiB count via absmax ----
__global__ void probe_fill(float* __restrict__ out, int n, float v) {
  int i = blockIdx.x * blockDim.x + threadIdx.x;
  if (i < n) out[i] = v;
}

// ---- weight prep: W fp32 (K,N) -> Wt bf16 (Nrows, Kpad), zero-padded ----
__global__ void transpose_bf16_kernel(const float* __restrict__ W, u16* __restrict__ Wt,
                                      int K, int N, int Kpad, int Nrows) {
  __shared__ float tile[32][33];
  int kb = blockIdx.x * 32, nb = blockIdx.y * 32;
  int tx = threadIdx.x & 31, ty = threadIdx.x >> 5;   // 32x8 threads
  #pragma unroll
  for (int i = ty; i < 32; i += 8) {
    int k = kb + i, n = nb + tx;
    tile[i][tx] = (k < K && n < N) ? W[(size_t)k * N + n] : 0.f;
  }
  __syncthreads();
  #pragma unroll
  for (int i = ty; i < 32; i += 8) {
    int n = nb + i, k = kb + tx;
    if (n < Nrows && k < Kpad)
      Wt[(size_t)n * Kpad + k] = f2bf(tile[tx][i]);
  }
}

// ---- embedding gather -> bf16, K padded 620->640 with zeros (stride 640) ----
__global__ void embed_kernel(const int* __restrict__ tokens, const float* __restrict__ emb,
                             u16* __restrict__ xbf) {
  int t = blockIdx.x;                 // 8192 rows (l*B+b)
  int tok = tokens[t];
  const float* src = emb + (size_t)tok * K0;
  u16* dst = xbf + (size_t)t * K0P;
  for (int k = threadIdx.x; k < K0P; k += blockDim.x)
    dst[k] = (k < K0) ? f2bf(src[k]) : (u16)0;
}

// ---- zero the pad columns [2400,2432) of a 2432-stride bf16 buffer ----
__global__ void zero_pad_x(u16* __restrict__ x) {
  int r = blockIdx.x * blockDim.x + threadIdx.x;
  if (r >= MR) return;
  uint4* p = (uint4*)(x + (size_t)r * KLP + KL);   // 64 B, 16-aligned
  p[0] = make_uint4(0, 0, 0, 0);
  p[1] = make_uint4(0, 0, 0, 0);
  p[2] = make_uint4(0, 0, 0, 0);
  p[3] = make_uint4(0, 0, 0, 0);
}

// ============================================================================
// NT GEMM, 256x256 tile, BK=64, 8 waves (2Mx4N), 8-phase schedule (T2+T3+T4+T5).
// C(M,N) = A(M,K)*Bt(N,K)^T, bf16 in/out, fp32 accum.
//
// LDS: As/Bs double-buffered 256x64 bf16 each = 128 KiB total, 1 block/CU.
// Swizzle (verified 0-conflict in prior rounds): LDS row r (128 B), 16-B chunk
// c holds global chunk c^(r&7); frag read at row (..+l16) uses chunk g^(l16&7).
//
// Per K-tile t (buffer p=t&1), 4 phases; phase q computes M-frags {2q,2q+1}
// x 4 N-frags x 2 ksteps = 16 MFMA. Staging runs 2 tiles ahead, 2 issues
// (64 rows x 128 B each) per phase; each staged region's readers retired at
// least one trailing barrier before the issue:
//   phase 0: stage A rows 64-127,192-255 of tile t+1 (other buffer; those rows
//            were last read in phases 2,3 of tile t-1 -> retired)
//   phase 1: stage B rows   0-127 of tile t+2 (B of buf p fully read phase 0)
//   phase 2: stage B rows 128-255 of tile t+2
//   phase 3: stage A rows 0-63,128-191 of tile t+2 (read in phases 0,1)
// One counted wait per tile: vmcnt(6) in phase 3 (6 newest = this tile's
// phase-1..3 issues), guaranteeing tile t+1 fully landed before its phase 0.
// Epilogue: t=NT-2 drains vmcnt(0); t=NT-1 stages nothing.
// ============================================================================
#define FRAG_A(i, OFF) (*(const bf16x8*)(pa + (wrl + (i) * 16 + l16) * 128 + (OFF)))
#define FRAG_B(j, OFF) (*(const bf16x8*)(pb + (wcl + (j) * 16 + l16) * 128 + (OFF)))

#define MFMA_Q(Q)                                                                      \
  _Pragma("unroll")                                                                    \
  for (int j = 0; j < 4; ++j) {                                                        \
    acc[2*(Q)][j]   = __builtin_amdgcn_mfma_f32_16x16x32_bf16(a0, bq[j][0], acc[2*(Q)][j],   0, 0, 0); \
    acc[2*(Q)][j]   = __builtin_amdgcn_mfma_f32_16x16x32_bf16(a1, bq[j][1], acc[2*(Q)][j],   0, 0, 0); \
    acc[2*(Q)+1][j] = __builtin_amdgcn_mfma_f32_16x16x32_bf16(a2, bq[j][0], acc[2*(Q)+1][j], 0, 0, 0); \
    acc[2*(Q)+1][j] = __builtin_amdgcn_mfma_f32_16x16x32_bf16(a3, bq[j][1], acc[2*(Q)+1][j], 0, 0, 0); \
  }

#define PHASE_TAIL(Q)                                                                  \
  __builtin_amdgcn_s_barrier();                                                        \
  asm volatile("s_waitcnt lgkmcnt(0)" ::: "memory");                                   \
  __builtin_amdgcn_sched_barrier(0);                                                   \
  __builtin_amdgcn_s_setprio(1);                                                       \
  MFMA_Q(Q);                                                                           \
  __builtin_amdgcn_s_setprio(0);                                                       \
  __builtin_amdgcn_s_barrier();

__global__ __launch_bounds__(512, 2)
void gemm_nt_bf16_256(const u16* __restrict__ A, const u16* __restrict__ Bt,
                      u16* __restrict__ C, int M, int N, int K) {
  __shared__ __align__(16) u16 As[2][256 * 64];   // 64 KB
  __shared__ __align__(16) u16 Bs[2][256 * 64];   // 64 KB
  const int tid  = threadIdx.x;
  const int lane = tid & 63;
  const int wave = tid >> 6;
  const int quad = lane >> 4;
  const int l16  = lane & 15;
  const int sw   = l16 & 7;
  const int wrl  = (wave >> 2) * 128;   // wave M offset within tile
  const int wcl  = (wave & 3) * 64;     // wave N offset within tile

  // bijective XCD-aware swizzle (our grids: 928 and 1216 blocks, both %8==0)
  const int nwg = gridDim.x * gridDim.y;
  const int lin = blockIdx.y * gridDim.x + blockIdx.x;
  const int swz = ((nwg & 7) == 0) ? ((lin & 7) * (nwg >> 3) + (lin >> 3)) : lin;
  const int bx = swz % gridDim.x;
  const int by = swz / gridDim.x;
  const size_t m0 = (size_t)bx * 256;
  const size_t n0 = (size_t)by * 256;

  const int NT = K >> 6;                // K-tiles (>= 2 for all our shapes)

  // staging: thread t covers LDS bytes t*16 of an 8 KB issue block (64 rows);
  // LDS row = t>>3, chunk t&7 holds global chunk (t&7)^(row&7)
  const int srow = tid >> 3;            // 0..63
  const int gch  = (tid & 7) ^ (srow & 7);
  const u16* aS = A  + (m0 + srow) * (size_t)K + gch * 8;
  const u16* bS = Bt + (n0 + srow) * (size_t)K + gch * 8;
  const size_t blkStep = (size_t)64 * K;   // +64 rows: (row&7) unchanged
  const int ldsOff = wave * 1024;          // wave covers 8 rows x 128 B per issue

  auto stgA = [&](int buf, int ib, int kt) {
    gload_lds16(aS + (size_t)kt * 64 + (size_t)ib * blkStep,
                (char*)As[buf] + ib * 8192 + ldsOff);
  };
  auto stgB = [&](int buf, int ib, int kt) {
    gload_lds16(bS + (size_t)kt * 64 + (size_t)ib * blkStep,
                (char*)Bs[buf] + ib * 8192 + ldsOff);
  };

  const int offk0 = (quad ^ sw) * 16;        // k in [k0,    k0+32)
  const int offk1 = ((quad + 4) ^ sw) * 16;  // k in [k0+32, k0+64)

  floatx4 acc[8][4] = {};

  // ---- prologue: tile 0 fully (8 issues) + tile 1 {B0..B3, A0, A2} (6) ----
  #pragma unroll
  for (int ib = 0; ib < 4; ++ib) stgA(0, ib, 0);
  #pragma unroll
  for (int ib = 0; ib < 4; ++ib) stgB(0, ib, 0);
  #pragma unroll
  for (int ib = 0; ib < 4; ++ib) stgB(1, ib, 1);
  stgA(1, 0, 1);
  stgA(1, 2, 1);
  asm volatile("s_waitcnt vmcnt(6)" ::: "memory");   // tile 0 landed
  __builtin_amdgcn_s_barrier();

  for (int t = 0; t < NT; ++t) {
    const int buf = t & 1;
    const char* pa = (const char*)As[buf];
    const char* pb = (const char*)Bs[buf];
    bf16x8 bq[4][2];

    // ---- phase 0: all B frags + A frags {0,1}; stage A1,A3 of tile t+1 ----
    {
      bf16x8 a0 = FRAG_A(0, offk0), a1 = FRAG_A(0, offk1);
      bf16x8 a2 = FRAG_A(1, offk0), a3 = FRAG_A(1, offk1);
      #pragma unroll
      for (int j = 0; j < 4; ++j) {
        bq[j][0] = FRAG_B(j, offk0);
        bq[j][1] = FRAG_B(j, offk1);
      }
      if (t + 1 < NT) { stgA(buf ^ 1, 1, t + 1); stgA(buf ^ 1, 3, t + 1); }
      PHASE_TAIL(0);
    }
    // ---- phase 1: A frags {2,3}; stage B0,B1 of tile t+2 ----
    {
      bf16x8 a0 = FRAG_A(2, offk0), a1 = FRAG_A(2, offk1);
      bf16x8 a2 = FRAG_A(3, offk0), a3 = FRAG_A(3, offk1);
      if (t + 2 < NT) { stgB(buf, 0, t + 2); stgB(buf, 1, t + 2); }
      PHASE_TAIL(1);
    }
    // ---- phase 2: A frags {4,5}; stage B2,B3 of tile t+2 ----
    {
      bf16x8 a0 = FRAG_A(4, offk0), a1 = FRAG_A(4, offk1);
      bf16x8 a2 = FRAG_A(5, offk0), a3 = FRAG_A(5, offk1);
      if (t + 2 < NT) { stgB(buf, 2, t + 2); stgB(buf, 3, t + 2); }
      PHASE_TAIL(2);
    }
    // ---- phase 3: A frags {6,7}; stage A0,A2 of tile t+2; counted vmcnt ----
    {
      bf16x8 a0 = FRAG_A(6, offk0), a1 = FRAG_A(6, offk1);
      bf16x8 a2 = FRAG_A(7, offk0), a3 = FRAG_A(7, offk1);
      if (t + 2 < NT) { stgA(buf, 0, t + 2); stgA(buf, 2, t + 2); }
      if (t + 2 < NT)      asm volatile("s_waitcnt vmcnt(6)" ::: "memory");
      else if (t + 1 < NT) asm volatile("s_waitcnt vmcnt(0)" ::: "memory");
      PHASE_TAIL(3);
    }
  }

  // C/D layout (m89/m91 verified): col = lane&15, row = quad*4 + reg
  #pragma unroll
  for (int i = 0; i < 8; ++i) {
    size_t row = m0 + wrl + i * 16 + quad * 4;
    #pragma unroll
    for (int j = 0; j < 4; ++j) {
      size_t col = n0 + wcl + j * 16 + l16;
      u16* cp = C + row * (size_t)N + col;
      #pragma unroll
      for (int r = 0; r < 4; ++r)
        cp[(size_t)r * N] = f2bf(acc[i][j][r]);
    }
  }
}

// ---- fused gates + chunked time scan + output mix (bf16 U in) ----
// Block = 32 chains (one b, 32 consecutive d) x 8 L-chunks of 32 steps.
// hbf (bf16) has row stride KLP=2432 (x-buffer); h32 (fp32) stride D.
// In-place skip aliasing (skip==hbf) is safe: per-element read-then-write
// within one thread iteration.
__global__ __launch_bounds__(256, 2)
void sru_scan_kernel(const u16* __restrict__ U, int SN,
                     const float* __restrict__ bias,
                     const u16* skip, int skipStride,
                     u16* hbf, float* h32) {
  __shared__ float A_l[8 * 32];
  __shared__ float C_l[8 * 32];
  const int tid = threadIdx.x;
  const int j  = tid >> 5;              // L-chunk 0..7
  const int dd = tid & 31;
  const int b  = blockIdx.x / (D_ / 32);
  const int d  = (blockIdx.x % (D_ / 32)) * 32 + dd;
  const float bfb = bias[d], brb = bias[D_ + d];
  const size_t rstep = (size_t)B_ * SN;
  const size_t sstep = (size_t)B_ * skipStride;
  const size_t hstep = (size_t)B_ * KLP;
  const size_t fstep = (size_t)B_ * D_;
  const u16* Up = U + (size_t)(j * 32) * rstep + (size_t)b * SN + d;
  const u16* Sp = skip + (size_t)(j * 32) * sstep + (size_t)b * skipStride + d;

  float cl[32], P[32];
  {
    float c = 0.f, A = 1.f;
    #pragma unroll
    for (int l = 0; l < 32; ++l) {
      float z  = bf2f(Up[l * rstep]);
      float fr = bf2f(Up[l * rstep + D_]);
      float f = fsigmoid(fr + bfb);
      c = f * c + (1.f - f) * z;
      A *= f;
      cl[l] = c; P[l] = A;
    }
    A_l[tid] = A;
    C_l[tid] = c;
  }
  __syncthreads();
  float Cin = 0.f;
  #pragma unroll
  for (int jj = 0; jj < 7; ++jj) {
    float a  = A_l[jj * 32 + dd];
    float cc = C_l[jj * 32 + dd];
    if (jj < j) Cin = a * Cin + cc;
  }

  u16*   hb = hbf ? hbf + (size_t)(j * 32) * hstep + (size_t)b * KLP + d : nullptr;
  float* hf = h32 ? h32 + (size_t)(j * 32) * fstep + (size_t)b * D_ + d : nullptr;
  #pragma unroll
  for (int l = 0; l < 32; ++l) {
    float rr = bf2f(Up[l * rstep + 2 * D_]);
    float xs = bf2f(Sp[l * sstep]);               // read BEFORE any aliased write
    float r = fsigmoid(rr + brb);
    float cf = cl[l] + P[l] * Cin;
    float h = r * ftanh(cf) + (1.f - r) * xs;
    if (hb) hb[l * hstep] = f2bf(h);
    if (hf) hf[l * fstep] = h;
  }
}

// ---- row-wise L2 normalize over D, in place ----
__global__ void normalize_kernel(float* __restrict__ x) {
  __shared__ float red[4];
  int row = blockIdx.x;     // 8192
  float* p = x + (size_t)row * D_;
  float s = 0.f;
  for (int d = threadIdx.x; d < D_; d += 256) { float v = p[d]; s += v * v; }
  #pragma unroll
  for (int o = 32; o > 0; o >>= 1) s += __shfl_down(s, o, 64);
  int lane = threadIdx.x & 63, w = threadIdx.x >> 6;
  if (lane == 0) red[w] = s;
  __syncthreads();
  if (threadIdx.x == 0) red[0] = 1.f / sqrtf(red[0] + red[1] + red[2] + red[3]);
  __syncthreads();
  float inv = red[0];
  for (int d = threadIdx.x; d < D_; d += 256) p[d] *= inv;
}

extern "C" void kernel_launch(void* const* d_in, const int* in_sizes, int n_in,
                              void* d_out, int out_size, void* d_ws, size_t ws_size,
                              hipStream_t stream) {
  const int*   tokens = (const int*)d_in[0];
  const float* emb = (const float*)d_in[1];
  const float* W0 = (const float*)d_in[2];
  const float* b0 = (const float*)d_in[3];
  const float* W1 = (const float*)d_in[4];
  const float* b1 = (const float*)d_in[5];
  const float* W2 = (const float*)d_in[6];
  const float* b2 = (const float*)d_in[7];
  const float* W3 = (const float*)d_in[8];
  const float* b3 = (const float*)d_in[9];
  float* out = (float*)d_out;

  if (ws_size < WS_REQ) {
    probe_fill<<<(out_size + 255) / 256, 256, 0, stream>>>(out, out_size,
                                                           (float)(ws_size >> 20));
    return;
  }

  char* ws = (char*)d_ws;
  u16* xa  = (u16*)(ws + OFF_XA);            // bf16 (8192,2432)
  u16* xb  = (u16*)(ws + OFF_XB);            // bf16 (8192,2432)
  u16* Ub  = (u16*)(ws + OFF_U);             // bf16 U
  u16* Wt0 = (u16*)(ws + OFF_WT0);           // (9728,640), aliases xa tail
  u16* x0  = xb;                             // (8192,640), aliases xb head
  u16* WtL = (u16*)((char*)Ub + WT_L_OFF);   // (7424,2432), aliases U tail

  dim3 blk(256);
  const int scanGrid = B_ * (D_ / 32);          // 2400 blocks
  const int padGrid = (MR + 255) / 256;

  // layer 0: U = x0 @ W0 (M=8192, N=9728, K=640); skip = U chunk 3
  embed_kernel<<<MR, 256, 0, stream>>>(tokens, emb, x0);
  transpose_bf16_kernel<<<dim3(K0P / 32, N0P / 32), blk, 0, stream>>>(W0, Wt0, K0, N0, K0P, N0P);
  gemm_nt_bf16_256<<<dim3(MR / 256, N0P / 256), 512, 0, stream>>>(x0, Wt0, Ub, MR, N0P, K0P);
  // Wt0 (xa tail) and x0 (xb head) now dead -> establish pad columns
  zero_pad_x<<<padGrid, 256, 0, stream>>>(xa);
  zero_pad_x<<<padGrid, 256, 0, stream>>>(xb);
  sru_scan_kernel<<<scanGrid, 256, 0, stream>>>(Ub, N0P, b0, Ub + 3 * D_, N0P, xa, nullptr);

  // layer 1 (WtL in U tail; layer-0 U fully dead after scan0,
  //          big GEMMs write U only through stride NLP)
  transpose_bf16_kernel<<<dim3(KLP / 32, NLP / 32), blk, 0, stream>>>(W1, WtL, KL, NL, KLP, NLP);
  gemm_nt_bf16_256<<<dim3(MR / 256, NLP / 256), 512, 0, stream>>>(xa, WtL, Ub, MR, NLP, KLP);
  sru_scan_kernel<<<scanGrid, 256, 0, stream>>>(Ub, NLP, b1, xa, KLP, xb, nullptr);

  // layer 2
  transpose_bf16_kernel<<<dim3(KLP / 32, NLP / 32), blk, 0, stream>>>(W2, WtL, KL, NL, KLP, NLP);
  gemm_nt_bf16_256<<<dim3(MR / 256, NLP / 256), 512, 0, stream>>>(xb, WtL, Ub, MR, NLP, KLP);
  sru_scan_kernel<<<scanGrid, 256, 0, stream>>>(Ub, NLP, b2, xb, KLP, xa, nullptr);

  // layer 3: h (fp32) straight to d_out
  transpose_bf16_kernel<<<dim3(KLP / 32, NLP / 32), blk, 0, stream>>>(W3, WtL, KL, NL, KLP, NLP);
  gemm_nt_bf16_256<<<dim3(MR / 256, NLP / 256), 512, 0, stream>>>(xa, WtL, Ub, MR, NLP, KLP);
  sru_scan_kernel<<<scanGrid, 256, 0, stream>>>(Ub, NLP, b3, xa, KLP, nullptr, out);

  normalize_kernel<<<MR, 256, 0, stream>>>(out);
}

// Round 2
// 1631.390 us; speedup vs baseline: 1.0089x; 1.0089x over previous
//
#include <hip/hip_runtime.h>
#include <cstdint>
#include <cstddef>

typedef unsigned short u16;
typedef unsigned char u8;

// Problem constants
constexpr int L_ = 256, B_ = 32, D_ = 2400;
constexpr int K0 = 620, K0P = 640;          // layer-0 K, padded (mult of 64)
constexpr int N0 = 9600, N0P = 9728;        // layer-0 N = 4*D, padded to 38*256
constexpr int NL = 7200, NLP = 7424;        // layers 1-3 N = 3*D, padded to 29*256
constexpr int KL = 2400, KLP = 2432;        // layers 1-3 K = D, padded to mult of 64
constexpr int MR = L_ * B_;                 // 8192 rows (32*256)

// ---- workspace carve-up (bytes; lifetimes audited against launch order) ----
constexpr size_t SZ_XBUF = (size_t)MR * KLP * 2;     // 39,845,888  bf16 x (stride 2432)
constexpr size_t SZ_UB   = (size_t)MR * N0P * 2;     // 159,383,552 bf16 U (stride 9728)
constexpr size_t OFF_XA  = 0;
constexpr size_t OFF_XB  = SZ_XBUF;
constexpr size_t OFF_U   = 2 * SZ_XBUF;
constexpr size_t WS_REQ  = OFF_U + SZ_UB;            // 239,075,328 (< 248.2 MB known-good)
// W0^T bf16 (9728,640) aliases xa tail: dead after gemm0; xa written first by scan0
constexpr size_t SZ_WT0  = (size_t)N0P * K0P * 2;    // 12,451,840
constexpr size_t OFF_WT0 = OFF_XA + SZ_XBUF - SZ_WT0;
static_assert(OFF_WT0 % 256 == 0, "");
// x0 bf16 (8192,640) aliases xb head: dead after gemm0; xb pads zeroed after gemm0
constexpr size_t SZ_X0   = (size_t)MR * K0P * 2;     // 10,485,760
static_assert(SZ_X0 <= SZ_XBUF, "");
// layers 1-3 W^T bf16 (7424,2432) alias U tail: layer-0 U dead after scan0,
// and big GEMMs write U only through stride NLP (first 121.6 MB)
constexpr size_t WT_L_OFF = (size_t)MR * NLP * 2;    // 121,634,816
static_assert(WT_L_OFF + (size_t)NLP * KLP * 2 <= SZ_UB, "WtL must fit in U tail");

typedef __bf16 bf16x8 __attribute__((ext_vector_type(8)));
typedef float floatx4 __attribute__((ext_vector_type(4)));

__device__ __forceinline__ u16 f2bf(float x) {
  unsigned u = __float_as_uint(x);
  unsigned r = 0x7fffu + ((u >> 16) & 1u);   // round-to-nearest-even
  return (u16)((u + r) >> 16);
}
__device__ __forceinline__ float bf2f(u16 v) {
  return __uint_as_float((unsigned)v << 16);
}
__device__ __forceinline__ float frcp(float x) { return __builtin_amdgcn_rcpf(x); }
__device__ __forceinline__ float fsigmoid(float x) { return frcp(1.f + __expf(-x)); }
__device__ __forceinline__ float ftanh(float x) {
  return 1.f - 2.f * frcp(__expf(2.f * x) + 1.f);   // saturates via inf/0
}

__device__ __forceinline__ void gload_lds16(const void* g, void* l) {
  __builtin_amdgcn_global_load_lds(
      (__attribute__((address_space(1))) void*)g,
      (__attribute__((address_space(3))) void*)l,
      16, 0, 0);
}

// ---- ws_size probe: if workspace too small, report its MiB count via absmax ----
__global__ void probe_fill(float* __restrict__ out, int n, float v) {
  int i = blockIdx.x * blockDim.x + threadIdx.x;
  if (i < n) out[i] = v;
}

// ---- weight prep: W fp32 (K,N) -> Wt bf16 (Nrows, Kpad), zero-padded ----
__global__ void transpose_bf16_kernel(const float* __restrict__ W, u16* __restrict__ Wt,
                                      int K, int N, int Kpad, int Nrows) {
  __shared__ float tile[32][33];
  int kb = blockIdx.x * 32, nb = blockIdx.y * 32;
  int tx = threadIdx.x & 31, ty = threadIdx.x >> 5;   // 32x8 threads
  #pragma unroll
  for (int i = ty; i < 32; i += 8) {
    int k = kb + i, n = nb + tx;
    tile[i][tx] = (k < K && n < N) ? W[(size_t)k * N + n] : 0.f;
  }
  __syncthreads();
  #pragma unroll
  for (int i = ty; i < 32; i += 8) {
    int n = nb + i, k = kb + tx;
    if (n < Nrows && k < Kpad)
      Wt[(size_t)n * Kpad + k] = f2bf(tile[tx][i]);
  }
}

// ---- embedding gather -> bf16, K padded 620->640 with zeros (stride 640) ----
__global__ void embed_kernel(const int* __restrict__ tokens, const float* __restrict__ emb,
                             u16* __restrict__ xbf) {
  int t = blockIdx.x;                 // 8192 rows (l*B+b)
  int tok = tokens[t];
  const float* src = emb + (size_t)tok * K0;
  u16* dst = xbf + (size_t)t * K0P;
  for (int k = threadIdx.x; k < K0P; k += blockDim.x)
    dst[k] = (k < K0) ? f2bf(src[k]) : (u16)0;
}

// ---- zero the pad columns [2400,2432) of a 2432-stride bf16 buffer ----
__global__ void zero_pad_x(u16* __restrict__ x) {
  int r = blockIdx.x * blockDim.x + threadIdx.x;
  if (r >= MR) return;
  uint4* p = (uint4*)(x + (size_t)r * KLP + KL);   // 64 B, 16-aligned
  p[0] = make_uint4(0, 0, 0, 0);
  p[1] = make_uint4(0, 0, 0, 0);
  p[2] = make_uint4(0, 0, 0, 0);
  p[3] = make_uint4(0, 0, 0, 0);
}

// ============================================================================
// NT GEMM, 256x256 tile, BK=64, 8 waves (2Mx4N), 8-phase schedule (T2+T3+T4+T5).
// C(M,N) = A(M,K)*Bt(N,K)^T, bf16 in/out, fp32 accum.
//
// Round-2 changes vs round 1 (post-mortem: MfmaUtil 41%, FETCH +35% vs 128^2):
//  * XCD swizzle REMOVED: FETCH rose 443->599 MB with it; working set is
//    L3-fit (A 40MB + B 36MB) where swizzle is known to cost; default lin
//    order is already panel-local (consecutive blocks share the B panel).
//  * Two-wait schedule: every retired load now has >= 4 phases of slack
//    (was 3 for the just-issued A1/A3 -> HBM-latency stalls at phase 3).
//
// LDS: As/Bs double-buffered 256x64 bf16 each = 128 KiB total, 1 block/CU.
// Swizzle (0-conflict verified): LDS row r (128 B), 16-B chunk c holds global
// chunk c^(r&7); frag read at row (..+l16) uses chunk g^(l16&7).
//
// Phase q computes M-frags {2q,2q+1} x 4 N-frags x 2 ksteps = 16 MFMA.
// A issue-block ib covers rows [64*ib,64*ib+64): ib0/ib2 read in phases 0-1,
// ib1/ib3 read in phases 2-3. B (all frags) read only in phase 0.
// Staging (2 issues/phase, 8 KB each):
//   ph0: T+1.A1,A3   (into buf^1; those rows last read by tile t-1 ph2/3)
//   ph1: T+2.B0,B1   (into buf; B of buf fully read at ph0)
//   ph2: T+2.B2,B3
//   ph3: T+2.A0,A2   (rows 0-63,128-191 of buf; read at ph0/ph1)
// Waits (oldest-first retirement bookkeeping, per-wave identical counts):
//   ph1: vmcnt(10) retires THIS tile's A1,A3 (issued t-1 ph0; needed ph2)
//        -> slack 5 phases.  [t=0: 10 outstanding -> no-op, correct]
//   ph3: vmcnt(8)  retires T+1.B0-3,A0,A2 (issued t-1 ph1..ph3; needed
//        t+1 ph0) -> slack >= 4 phases.
// Epilogue: t=NT-2: ph1 vmcnt(8), ph3 vmcnt(2); t=NT-1: ph1 vmcnt(0).
// Requires NT >= 3 (NT = 10 and 38 here).
// ============================================================================
#define FRAG_A(i, OFF) (*(const bf16x8*)(pa + (wrl + (i) * 16 + l16) * 128 + (OFF)))
#define FRAG_B(j, OFF) (*(const bf16x8*)(pb + (wcl + (j) * 16 + l16) * 128 + (OFF)))

#define MFMA_Q(Q)                                                                      \
  _Pragma("unroll")                                                                    \
  for (int j = 0; j < 4; ++j) {                                                        \
    acc[2*(Q)][j]   = __builtin_amdgcn_mfma_f32_16x16x32_bf16(a0, bq[j][0], acc[2*(Q)][j],   0, 0, 0); \
    acc[2*(Q)][j]   = __builtin_amdgcn_mfma_f32_16x16x32_bf16(a1, bq[j][1], acc[2*(Q)][j],   0, 0, 0); \
    acc[2*(Q)+1][j] = __builtin_amdgcn_mfma_f32_16x16x32_bf16(a2, bq[j][0], acc[2*(Q)+1][j], 0, 0, 0); \
    acc[2*(Q)+1][j] = __builtin_amdgcn_mfma_f32_16x16x32_bf16(a3, bq[j][1], acc[2*(Q)+1][j], 0, 0, 0); \
  }

#define PHASE_TAIL(Q)                                                                  \
  __builtin_amdgcn_s_barrier();                                                        \
  asm volatile("s_waitcnt lgkmcnt(0)" ::: "memory");                                   \
  __builtin_amdgcn_sched_barrier(0);                                                   \
  __builtin_amdgcn_s_setprio(1);                                                       \
  MFMA_Q(Q);                                                                           \
  __builtin_amdgcn_s_setprio(0);                                                       \
  __builtin_amdgcn_s_barrier();

__global__ __launch_bounds__(512, 2)
void gemm_nt_bf16_256(const u16* __restrict__ A, const u16* __restrict__ Bt,
                      u16* __restrict__ C, int M, int N, int K) {
  __shared__ __align__(16) u16 As[2][256 * 64];   // 64 KB
  __shared__ __align__(16) u16 Bs[2][256 * 64];   // 64 KB
  const int tid  = threadIdx.x;
  const int lane = tid & 63;
  const int wave = tid >> 6;
  const int quad = lane >> 4;
  const int l16  = lane & 15;
  const int sw   = l16 & 7;
  const int wrl  = (wave >> 2) * 128;   // wave M offset within tile
  const int wcl  = (wave & 3) * 64;     // wave N offset within tile

  const size_t m0 = (size_t)blockIdx.x * 256;
  const size_t n0 = (size_t)blockIdx.y * 256;

  const int NT = K >> 6;                // K-tiles (>= 3 for all our shapes)

  // staging: thread t covers LDS bytes t*16 of an 8 KB issue block (64 rows);
  // LDS row = t>>3, chunk t&7 holds global chunk (t&7)^(row&7)
  const int srow = tid >> 3;            // 0..63
  const int gch  = (tid & 7) ^ (srow & 7);
  const u16* aS = A  + (m0 + srow) * (size_t)K + gch * 8;
  const u16* bS = Bt + (n0 + srow) * (size_t)K + gch * 8;
  const size_t blkStep = (size_t)64 * K;   // +64 rows: (row&7) unchanged
  const int ldsOff = wave * 1024;          // wave covers 8 rows x 128 B per issue

  auto stgA = [&](int buf, int ib, int kt) {
    gload_lds16(aS + (size_t)kt * 64 + (size_t)ib * blkStep,
                (char*)As[buf] + ib * 8192 + ldsOff);
  };
  auto stgB = [&](int buf, int ib, int kt) {
    gload_lds16(bS + (size_t)kt * 64 + (size_t)ib * blkStep,
                (char*)Bs[buf] + ib * 8192 + ldsOff);
  };

  const int offk0 = (quad ^ sw) * 16;        // k in [k0,    k0+32)
  const int offk1 = ((quad + 4) ^ sw) * 16;  // k in [k0+32, k0+64)

  floatx4 acc[8][4] = {};

  // ---- prologue: tile 0 fully (8 issues) + tile 1 {B0..B3, A0, A2} (6) ----
  #pragma unroll
  for (int ib = 0; ib < 4; ++ib) stgA(0, ib, 0);
  #pragma unroll
  for (int ib = 0; ib < 4; ++ib) stgB(0, ib, 0);
  #pragma unroll
  for (int ib = 0; ib < 4; ++ib) stgB(1, ib, 1);
  stgA(1, 0, 1);
  stgA(1, 2, 1);
  asm volatile("s_waitcnt vmcnt(6)" ::: "memory");   // tile 0 landed
  __builtin_amdgcn_s_barrier();

  for (int t = 0; t < NT; ++t) {
    const int buf = t & 1;
    const char* pa = (const char*)As[buf];
    const char* pb = (const char*)Bs[buf];
    bf16x8 bq[4][2];

    // ---- phase 0: all B frags + A frags {0,1}; stage T+1.A1,A3 ----
    {
      bf16x8 a0 = FRAG_A(0, offk0), a1 = FRAG_A(0, offk1);
      bf16x8 a2 = FRAG_A(1, offk0), a3 = FRAG_A(1, offk1);
      #pragma unroll
      for (int j = 0; j < 4; ++j) {
        bq[j][0] = FRAG_B(j, offk0);
        bq[j][1] = FRAG_B(j, offk1);
      }
      if (t + 1 < NT) { stgA(buf ^ 1, 1, t + 1); stgA(buf ^ 1, 3, t + 1); }
      PHASE_TAIL(0);
    }
    // ---- phase 1: A frags {2,3}; stage T+2.B0,B1; retire this tile's A1,A3 ----
    {
      bf16x8 a0 = FRAG_A(2, offk0), a1 = FRAG_A(2, offk1);
      bf16x8 a2 = FRAG_A(3, offk0), a3 = FRAG_A(3, offk1);
      if (t + 2 < NT) { stgB(buf, 0, t + 2); stgB(buf, 1, t + 2); }
      if (t + 2 < NT)      asm volatile("s_waitcnt vmcnt(10)" ::: "memory");
      else if (t + 1 < NT) asm volatile("s_waitcnt vmcnt(8)" ::: "memory");
      else                 asm volatile("s_waitcnt vmcnt(0)" ::: "memory");
      PHASE_TAIL(1);
    }
    // ---- phase 2: A frags {4,5}; stage T+2.B2,B3 ----
    {
      bf16x8 a0 = FRAG_A(4, offk0), a1 = FRAG_A(4, offk1);
      bf16x8 a2 = FRAG_A(5, offk0), a3 = FRAG_A(5, offk1);
      if (t + 2 < NT) { stgB(buf, 2, t + 2); stgB(buf, 3, t + 2); }
      PHASE_TAIL(2);
    }
    // ---- phase 3: A frags {6,7}; stage T+2.A0,A2; retire T+1.{B,A0,A2} ----
    {
      bf16x8 a0 = FRAG_A(6, offk0), a1 = FRAG_A(6, offk1);
      bf16x8 a2 = FRAG_A(7, offk0), a3 = FRAG_A(7, offk1);
      if (t + 2 < NT) { stgA(buf, 0, t + 2); stgA(buf, 2, t + 2); }
      if (t + 2 < NT)      asm volatile("s_waitcnt vmcnt(8)" ::: "memory");
      else if (t + 1 < NT) asm volatile("s_waitcnt vmcnt(2)" ::: "memory");
      PHASE_TAIL(3);
    }
  }

  // C/D layout (m89/m91 verified): col = lane&15, row = quad*4 + reg
  #pragma unroll
  for (int i = 0; i < 8; ++i) {
    size_t row = m0 + wrl + i * 16 + quad * 4;
    #pragma unroll
    for (int j = 0; j < 4; ++j) {
      size_t col = n0 + wcl + j * 16 + l16;
      u16* cp = C + row * (size_t)N + col;
      #pragma unroll
      for (int r = 0; r < 4; ++r)
        cp[(size_t)r * N] = f2bf(acc[i][j][r]);
    }
  }
}

// ---- fused gates + chunked time scan + output mix (bf16 U in) ----
// Block = 32 chains (one b, 32 consecutive d) x 8 L-chunks of 32 steps.
// hbf (bf16) has row stride KLP=2432 (x-buffer); h32 (fp32) stride D.
// In-place skip aliasing (skip==hbf) is safe: per-element read-then-write
// within one thread iteration.
__global__ __launch_bounds__(256, 2)
void sru_scan_kernel(const u16* __restrict__ U, int SN,
                     const float* __restrict__ bias,
                     const u16* skip, int skipStride,
                     u16* hbf, float* h32) {
  __shared__ float A_l[8 * 32];
  __shared__ float C_l[8 * 32];
  const int tid = threadIdx.x;
  const int j  = tid >> 5;              // L-chunk 0..7
  const int dd = tid & 31;
  const int b  = blockIdx.x / (D_ / 32);
  const int d  = (blockIdx.x % (D_ / 32)) * 32 + dd;
  const float bfb = bias[d], brb = bias[D_ + d];
  const size_t rstep = (size_t)B_ * SN;
  const size_t sstep = (size_t)B_ * skipStride;
  const size_t hstep = (size_t)B_ * KLP;
  const size_t fstep = (size_t)B_ * D_;
  const u16* Up = U + (size_t)(j * 32) * rstep + (size_t)b * SN + d;
  const u16* Sp = skip + (size_t)(j * 32) * sstep + (size_t)b * skipStride + d;

  float cl[32], P[32];
  {
    float c = 0.f, A = 1.f;
    #pragma unroll
    for (int l = 0; l < 32; ++l) {
      float z  = bf2f(Up[l * rstep]);
      float fr = bf2f(Up[l * rstep + D_]);
      float f = fsigmoid(fr + bfb);
      c = f * c + (1.f - f) * z;
      A *= f;
      cl[l] = c; P[l] = A;
    }
    A_l[tid] = A;
    C_l[tid] = c;
  }
  __syncthreads();
  float Cin = 0.f;
  #pragma unroll
  for (int jj = 0; jj < 7; ++jj) {
    float a  = A_l[jj * 32 + dd];
    float cc = C_l[jj * 32 + dd];
    if (jj < j) Cin = a * Cin + cc;
  }

  u16*   hb = hbf ? hbf + (size_t)(j * 32) * hstep + (size_t)b * KLP + d : nullptr;
  float* hf = h32 ? h32 + (size_t)(j * 32) * fstep + (size_t)b * D_ + d : nullptr;
  #pragma unroll
  for (int l = 0; l < 32; ++l) {
    float rr = bf2f(Up[l * rstep + 2 * D_]);
    float xs = bf2f(Sp[l * sstep]);               // read BEFORE any aliased write
    float r = fsigmoid(rr + brb);
    float cf = cl[l] + P[l] * Cin;
    float h = r * ftanh(cf) + (1.f - r) * xs;
    if (hb) hb[l * hstep] = f2bf(h);
    if (hf) hf[l * fstep] = h;
  }
}

// ---- row-wise L2 normalize over D, in place ----
__global__ void normalize_kernel(float* __restrict__ x) {
  __shared__ float red[4];
  int row = blockIdx.x;     // 8192
  float* p = x + (size_t)row * D_;
  float s = 0.f;
  for (int d = threadIdx.x; d < D_; d += 256) { float v = p[d]; s += v * v; }
  #pragma unroll
  for (int o = 32; o > 0; o >>= 1) s += __shfl_down(s, o, 64);
  int lane = threadIdx.x & 63, w = threadIdx.x >> 6;
  if (lane == 0) red[w] = s;
  __syncthreads();
  if (threadIdx.x == 0) red[0] = 1.f / sqrtf(red[0] + red[1] + red[2] + red[3]);
  __syncthreads();
  float inv = red[0];
  for (int d = threadIdx.x; d < D_; d += 256) p[d] *= inv;
}

extern "C" void kernel_launch(void* const* d_in, const int* in_sizes, int n_in,
                              void* d_out, int out_size, void* d_ws, size_t ws_size,
                              hipStream_t stream) {
  const int*   tokens = (const int*)d_in[0];
  const float* emb = (const float*)d_in[1];
  const float* W0 = (const float*)d_in[2];
  const float* b0 = (const float*)d_in[3];
  const float* W1 = (const float*)d_in[4];
  const float* b1 = (const float*)d_in[5];
  const float* W2 = (const float*)d_in[6];
  const float* b2 = (const float*)d_in[7];
  const float* W3 = (const float*)d_in[8];
  const float* b3 = (const float*)d_in[9];
  float* out = (float*)d_out;

  if (ws_size < WS_REQ) {
    probe_fill<<<(out_size + 255) / 256, 256, 0, stream>>>(out, out_size,
                                                           (float)(ws_size >> 20));
    return;
  }

  char* ws = (char*)d_ws;
  u16* xa  = (u16*)(ws + OFF_XA);            // bf16 (8192,2432)
  u16* xb  = (u16*)(ws + OFF_XB);            // bf16 (8192,2432)
  u16* Ub  = (u16*)(ws + OFF_U);             // bf16 U
  u16* Wt0 = (u16*)(ws + OFF_WT0);           // (9728,640), aliases xa tail
  u16* x0  = xb;                             // (8192,640), aliases xb head
  u16* WtL = (u16*)((char*)Ub + WT_L_OFF);   // (7424,2432), aliases U tail

  dim3 blk(256);
  const int scanGrid = B_ * (D_ / 32);          // 2400 blocks
  const int padGrid = (MR + 255) / 256;

  // layer 0: U = x0 @ W0 (M=8192, N=9728, K=640); skip = U chunk 3
  embed_kernel<<<MR, 256, 0, stream>>>(tokens, emb, x0);
  transpose_bf16_kernel<<<dim3(K0P / 32, N0P / 32), blk, 0, stream>>>(W0, Wt0, K0, N0, K0P, N0P);
  gemm_nt_bf16_256<<<dim3(MR / 256, N0P / 256), 512, 0, stream>>>(x0, Wt0, Ub, MR, N0P, K0P);
  // Wt0 (xa tail) and x0 (xb head) now dead -> establish pad columns
  zero_pad_x<<<padGrid, 256, 0, stream>>>(xa);
  zero_pad_x<<<padGrid, 256, 0, stream>>>(xb);
  sru_scan_kernel<<<scanGrid, 256, 0, stream>>>(Ub, N0P, b0, Ub + 3 * D_, N0P, xa, nullptr);

  // layer 1 (WtL in U tail; layer-0 U fully dead after scan0,
  //          big GEMMs write U only through stride NLP)
  transpose_bf16_kernel<<<dim3(KLP / 32, NLP / 32), blk, 0, stream>>>(W1, WtL, KL, NL, KLP, NLP);
  gemm_nt_bf16_256<<<dim3(MR / 256, NLP / 256), 512, 0, stream>>>(xa, WtL, Ub, MR, NLP, KLP);
  sru_scan_kernel<<<scanGrid, 256, 0, stream>>>(Ub, NLP, b1, xa, KLP, xb, nullptr);

  // layer 2
  transpose_bf16_kernel<<<dim3(KLP / 32, NLP / 32), blk, 0, stream>>>(W2, WtL, KL, NL, KLP, NLP);
  gemm_nt_bf16_256<<<dim3(MR / 256, NLP / 256), 512, 0, stream>>>(xb, WtL, Ub, MR, NLP, KLP);
  sru_scan_kernel<<<scanGrid, 256, 0, stream>>>(Ub, NLP, b2, xb, KLP, xa, nullptr);

  // layer 3: h (fp32) straight to d_out
  transpose_bf16_kernel<<<dim3(KLP / 32, NLP / 32), blk, 0, stream>>>(W3, WtL, KL, NL, KLP, NLP);
  gemm_nt_bf16_256<<<dim3(MR / 256, NLP / 256), 512, 0, stream>>>(xa, WtL, Ub, MR, NLP, KLP);
  sru_scan_kernel<<<scanGrid, 256, 0, stream>>>(Ub, NLP, b3, xa, KLP, nullptr, out);

  normalize_kernel<<<MR, 256, 0, stream>>>(out);
}